// Round 2
// baseline (395.151 us; speedup 1.0000x reference)
//
#include <hip/hip_runtime.h>
#include <hip/hip_fp16.h>
#include <math.h>

// GCN 3-layer: out = Â relu(Â relu(Â x W1 + b1) W2 + b2) W3 + b3, Â = D^-1/2(A+I)D^-1/2
// Layer 3 reordered: Â(h2 W3) = (Â h2) W3  -> aggregate in 64-dim, then GEMM 64->112.
// CSR built once per launch via 2-pass radix sort on dst.
// Gathered intermediates stored as fp16 (128B rows = 1 cache line).
// agg: 4 nodes per wave, wave-wide index preload + 64 gathers in flight before
// consumption -> one gather latency per 4 nodes (was: one per node, latency-bound).

#define IN_DIM 128
#define HID 64
#define OUT_DIM 112
#define SCAN_TILE 1024   // elems per node-scan block: 256 threads x 4
#define LSHIFT 7         // 128 nodes per fine bucket
#define LMASK 127
#define MAXBUCK 1024     // supports n <= 131072
#define CHUNK 8192       // edges per coarse-pass block

// ---- pass 1a: per-chunk histogram of coarse buckets -> H[chunk*nbuck + b] ----
__global__ __launch_bounds__(256) void coarse_hist_kernel(const int* __restrict__ dst,
                                                          int* __restrict__ H,
                                                          int E, int nbuck) {
  __shared__ int hist[MAXBUCK];
  for (int i = threadIdx.x; i < nbuck; i += 256) hist[i] = 0;
  __syncthreads();
  int lo = blockIdx.x * CHUNK;
  int hi = min(E, lo + CHUNK);
  for (int i = lo + threadIdx.x; i < hi; i += 256)
    atomicAdd(&hist[dst[i] >> LSHIFT], 1);
  __syncthreads();
  int* Hrow = &H[(size_t)blockIdx.x * nbuck];
  for (int i = threadIdx.x; i < nbuck; i += 256) Hrow[i] = hist[i];
}

// ---- pass 1b: column totals of H -> btotal[b].  One WAVE per bucket. ----
__global__ __launch_bounds__(256) void btotal_kernel(const int* __restrict__ H,
                                                     int* __restrict__ btotal,
                                                     int nchunk, int nbuck) {
  int wv = threadIdx.x >> 6, lane = threadIdx.x & 63;
  int b = blockIdx.x * 4 + wv;
  if (b >= nbuck) return;
  int s = 0;
  for (int c = lane; c < nchunk; c += 64) s += H[(size_t)c * nbuck + b];
#pragma unroll
  for (int off = 1; off < 64; off <<= 1) s += __shfl_xor(s, off);
  if (lane == 0) btotal[b] = s;
}

// ---- pass 1c: exclusive scan of btotal -> bbase[0..nbuck] (single block) ----
__global__ __launch_bounds__(1024) void bbase_scan_kernel(const int* __restrict__ btotal,
                                                          int* __restrict__ bbase, int nbuck) {
  __shared__ int sh[1024];
  int t = threadIdx.x;
  int v = (t < nbuck) ? btotal[t] : 0;
  sh[t] = v;
  __syncthreads();
  for (int off = 1; off < 1024; off <<= 1) {
    int u = (t >= off) ? sh[t - off] : 0;
    __syncthreads();
    sh[t] += u;
    __syncthreads();
  }
  if (t < nbuck) bbase[t] = sh[t] - v;
  if (t == 1023) bbase[nbuck] = sh[1023];
}

// ---- pass 1d: H[c][b] <- bbase[b] + prefix over chunks.  One WAVE per bucket,
// shfl-scan over 64 chunks at a time (parallel; replaces 196-deep serial loop). ----
__global__ __launch_bounds__(256) void chunk_offset_kernel(int* __restrict__ H,
                                                           const int* __restrict__ bbase,
                                                           int nchunk, int nbuck) {
  int wv = threadIdx.x >> 6, lane = threadIdx.x & 63;
  int b = blockIdx.x * 4 + wv;
  if (b >= nbuck) return;
  int run = bbase[b];
  for (int c0 = 0; c0 < nchunk; c0 += 64) {
    int c = c0 + lane;
    int v = (c < nchunk) ? H[(size_t)c * nbuck + b] : 0;
    int incl = v;
#pragma unroll
    for (int off = 1; off < 64; off <<= 1) {
      int u = __shfl_up(incl, off);
      if (lane >= off) incl += u;
    }
    if (c < nchunk) H[(size_t)c * nbuck + b] = run + incl - v;
    run += __shfl(incl, 63);
  }
}

// ---- pass 1e: scatter edges into coarse-bucket runs as packed (src<<7 | dst&127) ----
__global__ __launch_bounds__(256) void coarse_scatter_kernel(const int* __restrict__ src,
                                                             const int* __restrict__ dst,
                                                             const int* __restrict__ H,
                                                             int* __restrict__ packed,
                                                             int E, int nbuck) {
  __shared__ int cur[MAXBUCK];
  const int* Hrow = &H[(size_t)blockIdx.x * nbuck];
  for (int i = threadIdx.x; i < nbuck; i += 256) cur[i] = Hrow[i];
  __syncthreads();
  int lo = blockIdx.x * CHUNK;
  int hi = min(E, lo + CHUNK);
  for (int i = lo + threadIdx.x; i < hi; i += 256) {
    int s = src[i], d = dst[i];
    int b = d >> LSHIFT;
    int pos = atomicAdd(&cur[b], 1);
    packed[pos] = (s << LSHIFT) | (d & LMASK);
  }
}

// ---- pass 2a: per-bucket node-degree histogram -> cnt ----
__global__ __launch_bounds__(256) void fine_count_kernel(const int* __restrict__ packed,
                                                         const int* __restrict__ bbase,
                                                         int* __restrict__ cnt, int n) {
  int b = blockIdx.x;
  __shared__ int hist[128];
  int t = threadIdx.x;
  if (t < 128) hist[t] = 0;
  __syncthreads();
  int e0 = bbase[b], e1 = bbase[b + 1];
  for (int e = e0 + t; e < e1; e += 256) atomicAdd(&hist[packed[e] & LMASK], 1);
  __syncthreads();
  int node = b * 128 + t;
  if (t < 128 && node < n) cnt[node] = hist[t];
}

// ---- pass 2b: per-bucket fill of ssrc ----
__global__ __launch_bounds__(256) void fine_scatter_kernel(const int* __restrict__ packed,
                                                           const int* __restrict__ bbase,
                                                           const int* __restrict__ row_start,
                                                           int* __restrict__ ssrc, int n) {
  int b = blockIdx.x;
  __shared__ int cur[128];
  int t = threadIdx.x;
  if (t < 128) {
    int node = b * 128 + t;
    cur[t] = (node < n) ? row_start[node] : 0;
  }
  __syncthreads();
  int e0 = bbase[b], e1 = bbase[b + 1];
  for (int e = e0 + t; e < e1; e += 256) {
    int p = packed[e];
    int slot = atomicAdd(&cur[p & LMASK], 1);
    ssrc[slot] = p >> LSHIFT;
  }
}

__global__ __launch_bounds__(256) void dinv_kernel(const int* __restrict__ cnt,
                                                   float* __restrict__ dinv, int n) {
  int i = blockIdx.x * 256 + threadIdx.x;
  if (i < n) dinv[i] = 1.0f / sqrtf((float)(cnt[i] + 1));  // +1 = self loop
}

// ---- hierarchical exclusive scan over node counts -> row_start ----

__global__ __launch_bounds__(256) void scan_partial_kernel(const int* __restrict__ cnt,
                                                           int* __restrict__ blocksum,
                                                           int n) {
  int t = threadIdx.x;
  int base = blockIdx.x * SCAN_TILE + t * 4;
  int s = 0;
  if (base + 4 <= n) {
    int4 v = *reinterpret_cast<const int4*>(&cnt[base]);
    s = v.x + v.y + v.z + v.w;
  } else {
    for (int i = 0; i < 4; ++i)
      if (base + i < n) s += cnt[base + i];
  }
#pragma unroll
  for (int off = 1; off < 64; off <<= 1) s += __shfl_xor(s, off);
  __shared__ int wsum[4];
  int lane = t & 63, wv = t >> 6;
  if (lane == 0) wsum[wv] = s;
  __syncthreads();
  if (t == 0) blocksum[blockIdx.x] = wsum[0] + wsum[1] + wsum[2] + wsum[3];
}

__global__ __launch_bounds__(1024) void scan_blocksums_kernel(int* __restrict__ blocksum,
                                                              int* __restrict__ total_out,
                                                              int nb) {
  __shared__ int sh[1024];
  int t = threadIdx.x;
  int v = (t < nb) ? blocksum[t] : 0;
  sh[t] = v;
  __syncthreads();
  for (int off = 1; off < 1024; off <<= 1) {
    int u = (t >= off) ? sh[t - off] : 0;
    __syncthreads();
    sh[t] += u;
    __syncthreads();
  }
  if (t < nb) blocksum[t] = sh[t] - v;  // exclusive
  if (t == 1023) *total_out = sh[1023]; // grand total
}

__global__ __launch_bounds__(256) void scan_final_kernel(const int* __restrict__ cnt,
                                                         const int* __restrict__ blocksum,
                                                         int* __restrict__ row_start, int n) {
  int t = threadIdx.x;
  int base = blockIdx.x * SCAN_TILE + t * 4;
  int v0 = 0, v1 = 0, v2 = 0, v3 = 0;
  if (base + 4 <= n) {
    int4 v = *reinterpret_cast<const int4*>(&cnt[base]);
    v0 = v.x; v1 = v.y; v2 = v.z; v3 = v.w;
  } else {
    if (base + 0 < n) v0 = cnt[base + 0];
    if (base + 1 < n) v1 = cnt[base + 1];
    if (base + 2 < n) v2 = cnt[base + 2];
    if (base + 3 < n) v3 = cnt[base + 3];
  }
  int s = v0 + v1 + v2 + v3;
  __shared__ int sh[256];
  sh[t] = s;
  __syncthreads();
  for (int off = 1; off < 256; off <<= 1) {
    int u = (t >= off) ? sh[t - off] : 0;
    __syncthreads();
    sh[t] += u;
    __syncthreads();
  }
  int run = blocksum[blockIdx.x] + sh[t] - s;
  int p0 = run, p1 = run + v0, p2 = p1 + v1, p3 = p2 + v2;
  if (base + 4 <= n) {
    *reinterpret_cast<int4*>(&row_start[base]) = make_int4(p0, p1, p2, p3);
  } else {
    if (base + 0 < n) row_start[base + 0] = p0;
    if (base + 1 < n) row_start[base + 1] = p1;
    if (base + 2 < n) row_start[base + 2] = p2;
    if (base + 3 < n) row_start[base + 3] = p3;
  }
}

// ---- K-chunked LDS-tiled fp32 GEMM ----
// G[r][c] = (X[r][:].W[:][c]) * (DINV?dinv[r]:1) + (BIAS?bias[c]:0)
// OUTH: store as __half (RN) -- feeds the fp16 gather path of agg_kernel.
template <int K, int C, int BK, bool DINV, bool BIAS, bool OUTH>
__global__ __launch_bounds__(256, 4) void gemm_scale_kernel(const float* __restrict__ X,
                                                            const float* __restrict__ W,
                                                            const float* __restrict__ dinv,
                                                            const float* __restrict__ bias,
                                                            void* __restrict__ G, int n) {
  constexpr int Cp = ((C + 63) / 64) * 64;  // 64 or 128
  constexpr int CQ = Cp / 4;                // col-quads: 16 or 32
  constexpr int RG = 256 / CQ;              // row-groups: 16 or 8
  constexpr int RPB = RG * 4;               // rows per block: 64 or 32
  constexpr int XP = BK + 4;                // padded LDS pitch (16B-aligned)
  constexpr int XQ = BK / 4;                // x quads per row per chunk
  constexpr int NXQ = RPB * XQ;             // x quads per chunk
  constexpr int NWQ = BK * CQ;              // w quads per chunk

  __shared__ float Xs[RPB * XP];
  __shared__ float Ws[BK * Cp];

  const int tid = threadIdx.x;
  const int rbase = blockIdx.x * RPB;
  const int ct = tid % CQ, rt = tid / CQ;
  const int c0 = ct * 4, r0 = rt * 4;

  float acc[4][4];
#pragma unroll
  for (int a = 0; a < 4; ++a)
#pragma unroll
    for (int b = 0; b < 4; ++b) acc[a][b] = 0.f;

  for (int kb = 0; kb < K; kb += BK) {
    if (kb > 0) __syncthreads();  // protect LDS reuse across chunks
    // stage X chunk (coalesced float4; tail rows clamped, stores guarded later)
#pragma unroll
    for (int q = tid; q < NXQ; q += 256) {
      int r = q / XQ, j = q % XQ;
      int grow = rbase + r;
      if (grow >= n) grow = n - 1;
      *reinterpret_cast<float4*>(&Xs[r * XP + j * 4]) =
          *reinterpret_cast<const float4*>(&X[(size_t)grow * K + kb + j * 4]);
    }
    // stage W chunk (zero-fill padded cols)
#pragma unroll
    for (int q = tid; q < NWQ; q += 256) {
      int k = q / CQ, cq = q % CQ, c = cq * 4;
      float4 v = make_float4(0.f, 0.f, 0.f, 0.f);
      if (c < C) v = *reinterpret_cast<const float4*>(&W[(size_t)(kb + k) * C + c]);
      *reinterpret_cast<float4*>(&Ws[k * Cp + c]) = v;
    }
    __syncthreads();

#pragma unroll 2
    for (int k = 0; k < BK; k += 4) {
      float4 w0 = *reinterpret_cast<const float4*>(&Ws[(k + 0) * Cp + c0]);
      float4 w1 = *reinterpret_cast<const float4*>(&Ws[(k + 1) * Cp + c0]);
      float4 w2 = *reinterpret_cast<const float4*>(&Ws[(k + 2) * Cp + c0]);
      float4 w3 = *reinterpret_cast<const float4*>(&Ws[(k + 3) * Cp + c0]);
#pragma unroll
      for (int rr = 0; rr < 4; ++rr) {
        float4 xv = *reinterpret_cast<const float4*>(&Xs[(r0 + rr) * XP + k]);
        acc[rr][0] = fmaf(xv.w, w3.x, fmaf(xv.z, w2.x, fmaf(xv.y, w1.x, fmaf(xv.x, w0.x, acc[rr][0]))));
        acc[rr][1] = fmaf(xv.w, w3.y, fmaf(xv.z, w2.y, fmaf(xv.y, w1.y, fmaf(xv.x, w0.y, acc[rr][1]))));
        acc[rr][2] = fmaf(xv.w, w3.z, fmaf(xv.z, w2.z, fmaf(xv.y, w1.z, fmaf(xv.x, w0.z, acc[rr][2]))));
        acc[rr][3] = fmaf(xv.w, w3.w, fmaf(xv.z, w2.w, fmaf(xv.y, w1.w, fmaf(xv.x, w0.w, acc[rr][3]))));
      }
    }
  }

#pragma unroll
  for (int rr = 0; rr < 4; ++rr) {
    int row = rbase + r0 + rr;
    if (row < n && c0 < C) {
      float s = DINV ? dinv[row] : 1.0f;
      float4 v;
      v.x = acc[rr][0] * s;
      v.y = acc[rr][1] * s;
      v.z = acc[rr][2] * s;
      v.w = acc[rr][3] * s;
      if (BIAS) {
        float4 bv = *reinterpret_cast<const float4*>(&bias[c0]);
        v.x += bv.x; v.y += bv.y; v.z += bv.z; v.w += bv.w;
      }
      if (OUTH) {
        union { __half2 h2[2]; float2 f2; } u;
        u.h2[0] = __floats2half2_rn(v.x, v.y);
        u.h2[1] = __floats2half2_rn(v.z, v.w);
        *reinterpret_cast<float2*>(&reinterpret_cast<__half*>(G)[(size_t)row * C + c0]) = u.f2;
      } else {
        *reinterpret_cast<float4*>(&reinterpret_cast<float*>(G)[(size_t)row * C + c0]) = v;
      }
    }
  }
}

// out[d][c] = post( dinv[d]*(g[d][c] + sum_{e in row d} g[ssrc[e]][c]) [+ bias[c]] )
// g is fp16 (128B rows, 1 cache line).  4 consecutive nodes per wave.  Lanes split
// into two 32-lane halves processing even/odd edges; each lane holds a half2
// (channels 2q,2q+1).  Per node, the index list is loaded with ONE wave-wide load
// (lane t = edge t, deg<=64) and distributed via __shfl; gathers for all 4 nodes
// (16 slots/half each, deg<=32 fast path) are issued before any consumption ->
// one gather latency per 4 nodes.  Wave-uniform continuation for deg>32 / >64.
template <int C, bool RELU, bool BIAS, bool TSCALE, bool OUTH>
__global__ __launch_bounds__(256) void agg_kernel(const __half* __restrict__ g,
                                                  const int* __restrict__ row_start,
                                                  const int* __restrict__ ssrc,
                                                  const float* __restrict__ dinv,
                                                  const float* __restrict__ bias,
                                                  void* __restrict__ out, int n, int E) {
  static_assert(C == 64, "agg assumes 64 channels");
  const int tid = threadIdx.x;
  const int wv = tid >> 6;
  const int lane = tid & 63;
  const int h = lane >> 5;   // half-wave: even (h=0) / odd (h=1) edge slots
  const int q = lane & 31;   // channel-pair index: channels {2q, 2q+1}
  const int wid = blockIdx.x * 4 + wv;
  const int base = wid * 4;  // first of this wave's 4 nodes
  if (base >= n) return;
  const __half2* g2 = reinterpret_cast<const __half2*>(g);

  // ---- prologue: 4 independent chains issued in parallel ----
  int rs[5];
#pragma unroll
  for (int j = 0; j < 5; ++j) rs[j] = row_start[min(base + j, n)];
  int e0[4], deg[4];
#pragma unroll
  for (int j = 0; j < 4; ++j) { e0[j] = rs[j]; deg[j] = rs[j + 1] - rs[j]; }

  // wave-wide index preload: lane t of midx[j] = ssrc[e0_j + t] (covers deg<=64)
  int midx[4];
#pragma unroll
  for (int j = 0; j < 4; ++j) {
    int off = (lane < deg[j]) ? lane : (deg[j] > 0 ? deg[j] - 1 : 0);
    midx[j] = ssrc[min(e0[j] + off, E - 1)];
  }

  float2 acc[4];
  float di[4];
#pragma unroll
  for (int j = 0; j < 4; ++j) {
    int node = base + j;
    int cl = (node < n) ? node : base;
    float2 sv = __half22float2(g2[(size_t)cl * 32 + q]);  // self-loop row
    acc[j] = (h == 0 && node < n) ? sv : make_float2(0.f, 0.f);
    di[j] = dinv[cl];
  }

  // ---- fast path: 64 gathers (4 nodes x 16 slots/half) issued back-to-back ----
  __half2 vb[4][16];
#pragma unroll
  for (int j = 0; j < 4; ++j) {
#pragma unroll
    for (int i = 0; i < 16; ++i) {
      int t = 2 * i + h;  // edge slot within row (this half covers t ≡ h mod 2)
      int s = (t < deg[j]) ? __shfl(midx[j], t) : base;  // dummy: cached row
      vb[j][i] = g2[(size_t)s * 32 + q];
    }
  }
#pragma unroll
  for (int j = 0; j < 4; ++j) {
#pragma unroll
    for (int i = 0; i < 16; ++i) {
      int t = 2 * i + h;
      if (t < deg[j]) {
        float2 f = __half22float2(vb[j][i]);
        acc[j].x += f.x; acc[j].y += f.y;
      }
    }
  }

  // ---- continuation: deg>32 (wave-uniform branch; ~0.02% of nodes) ----
#pragma unroll
  for (int j = 0; j < 4; ++j) {
    if (deg[j] > 32) {
      __half2 vc[16];
#pragma unroll
      for (int i = 0; i < 16; ++i) {
        int t = 32 + 2 * i + h;
        int s = (t < deg[j]) ? __shfl(midx[j], t) : base;
        vc[i] = g2[(size_t)s * 32 + q];
      }
#pragma unroll
      for (int i = 0; i < 16; ++i) {
        int t = 32 + 2 * i + h;
        if (t < deg[j]) {
          float2 f = __half22float2(vc[i]);
          acc[j].x += f.x; acc[j].y += f.y;
        }
      }
      for (int t = 64 + h; t < deg[j]; t += 2) {  // deg>64: direct loads
        int s = ssrc[e0[j] + t];
        float2 f = __half22float2(g2[(size_t)s * 32 + q]);
        acc[j].x += f.x; acc[j].y += f.y;
      }
    }
  }

  // ---- combine halves + epilogue ----
#pragma unroll
  for (int j = 0; j < 4; ++j) {
    acc[j].x += __shfl_xor(acc[j].x, 32);
    acc[j].y += __shfl_xor(acc[j].y, 32);
  }
  if (h == 0) {
#pragma unroll
    for (int j = 0; j < 4; ++j) {
      int node = base + j;
      if (node < n) {
        float d = di[j];
        float rx = acc[j].x * d, ry = acc[j].y * d;
        if (BIAS) {
          float2 bv = *reinterpret_cast<const float2*>(&bias[2 * q]);
          rx += bv.x; ry += bv.y;
        }
        if (RELU) { rx = fmaxf(rx, 0.f); ry = fmaxf(ry, 0.f); }
        if (TSCALE) { rx *= d; ry *= d; }
        if (OUTH) {
          reinterpret_cast<__half2*>(out)[(size_t)node * 32 + q] = __floats2half2_rn(rx, ry);
        } else {
          reinterpret_cast<float2*>(out)[(size_t)node * 32 + q] = make_float2(rx, ry);
        }
      }
    }
  }
}

extern "C" void kernel_launch(void* const* d_in, const int* in_sizes, int n_in,
                              void* d_out, int out_size, void* d_ws, size_t ws_size,
                              hipStream_t stream) {
  const float* x = (const float*)d_in[0];
  const int* ei = (const int*)d_in[1];
  const float* W1 = (const float*)d_in[2];
  const float* b1 = (const float*)d_in[3];
  const float* W2 = (const float*)d_in[4];
  const float* b2 = (const float*)d_in[5];
  const float* W3 = (const float*)d_in[6];
  const float* b3 = (const float*)d_in[7];
  float* out = (float*)d_out;

  const int n = in_sizes[0] / IN_DIM;  // 100000
  const int E = in_sizes[1] / 2;       // 1600000
  const int* src = ei;
  const int* dst = ei + E;
  const int nbuck = (n + LMASK) >> LSHIFT;        // 782
  const int nchunk = (E + CHUNK - 1) / CHUNK;     // 196

  char* p = (char*)d_ws;
  auto alloc = [&](size_t bytes) {
    char* q = p;
    p += (bytes + 255) & ~(size_t)255;
    return q;
  };
  float* dinv = (float*)alloc((size_t)n * 4);
  int* row_start = (int*)alloc((size_t)(n + 1) * 4);
  int* cnt = (int*)alloc((size_t)n * 4);
  int* blocksum = (int*)alloc((size_t)1024 * 4);
  int* btotal = (int*)alloc((size_t)MAXBUCK * 4);
  int* bbase = (int*)alloc((size_t)(MAXBUCK + 1) * 4);
  int* H = (int*)alloc((size_t)nchunk * nbuck * 4);
  int* packed = (int*)alloc((size_t)E * 4);
  int* ssrc = (int*)alloc((size_t)E * 4);
  __half* gh = (__half*)alloc((size_t)n * HID * 2);   // fp16 gather buffer (GEMM1/2 out)
  __half* th = (__half*)alloc((size_t)n * HID * 2);   // fp16 pre-scaled t (agg2 out, agg3 in)
  float* f32b = (float*)alloc((size_t)n * HID * 4);   // fp32 GEMM input buffer

  const int NB = (n + SCAN_TILE - 1) / SCAN_TILE;  // 98 node-scan blocks
  const int WGRID = (nbuck + 3) / 4;               // wave-per-bucket grids
  const int AGRID = (n + 15) / 16;                 // agg: 4 waves x 4 nodes per block

  // ---- CSR build via 2-pass radix sort (once; shared by all 3 layers) ----
  coarse_hist_kernel<<<nchunk, 256, 0, stream>>>(dst, H, E, nbuck);
  btotal_kernel<<<WGRID, 256, 0, stream>>>(H, btotal, nchunk, nbuck);
  bbase_scan_kernel<<<1, 1024, 0, stream>>>(btotal, bbase, nbuck);
  chunk_offset_kernel<<<WGRID, 256, 0, stream>>>(H, bbase, nchunk, nbuck);
  coarse_scatter_kernel<<<nchunk, 256, 0, stream>>>(src, dst, H, packed, E, nbuck);
  fine_count_kernel<<<nbuck, 256, 0, stream>>>(packed, bbase, cnt, n);
  dinv_kernel<<<(n + 255) / 256, 256, 0, stream>>>(cnt, dinv, n);
  scan_partial_kernel<<<NB, 256, 0, stream>>>(cnt, blocksum, n);
  scan_blocksums_kernel<<<1, 1024, 0, stream>>>(blocksum, &row_start[n], NB);
  scan_final_kernel<<<NB, 256, 0, stream>>>(cnt, blocksum, row_start, n);
  fine_scatter_kernel<<<nbuck, 256, 0, stream>>>(packed, bbase, row_start, ssrc, n);

  // ---- layer 1: g1=(x W1)*dinv_row (fp16) ; h1=relu(agg*dinv + b1) (fp32) ----
  gemm_scale_kernel<IN_DIM, HID, 64, true, false, true><<<(n + 63) / 64, 256, 0, stream>>>(x, W1, dinv, nullptr, gh, n);
  agg_kernel<HID, true, true, false, false><<<AGRID, 256, 0, stream>>>(gh, row_start, ssrc, dinv, b1, f32b, n, E);

  // ---- layer 2: g2=(h1 W2)*dinv_row (fp16) ; t = relu(agg*dinv + b2)*dinv (fp16, pre-scaled for L3) ----
  gemm_scale_kernel<HID, HID, 64, true, false, true><<<(n + 63) / 64, 256, 0, stream>>>(f32b, W2, dinv, nullptr, gh, n);
  agg_kernel<HID, true, true, true, true><<<AGRID, 256, 0, stream>>>(gh, row_start, ssrc, dinv, b2, th, n, E);

  // ---- layer 3 (reordered): z = dinv*(t + sum t[s]) (fp32) ; out = z W3 + b3 ----
  agg_kernel<HID, false, false, false, false><<<AGRID, 256, 0, stream>>>(th, row_start, ssrc, dinv, nullptr, f32b, n, E);
  gemm_scale_kernel<HID, OUT_DIM, 32, false, true, false><<<(n + 31) / 32, 256, 0, stream>>>(f32b, W3, dinv, b3, out, n);
}

// Round 3
// 355.875 us; speedup vs baseline: 1.1104x; 1.1104x over previous
//
#include <hip/hip_runtime.h>
#include <hip/hip_fp16.h>
#include <math.h>

// GCN 3-layer: out = Â relu(Â relu(Â x W1 + b1) W2 + b2) W3 + b3, Â = D^-1/2(A+I)D^-1/2
// Layer 3 reordered: Â(h2 W3) = (Â h2) W3  -> aggregate in 64-dim, then GEMM 64->112.
// CSR built once per launch via 2-pass radix sort on dst.
// All dense GEMMs use v_mfma_f32_16x16x32_f16 (fp16 in, fp32 acc); all node-feature
// intermediates stored fp16 (128B rows = 1 cache line) -- MFMA rounds A to fp16
// anyway, so fp16 storage is free accuracy-wise and halves gather/GEMM traffic.
// agg: R1 structure (1 node/wave, even/odd half-wave edges, 16 gathers in flight).

#define IN_DIM 128
#define HID 64
#define OUT_DIM 112
#define SCAN_TILE 1024   // elems per node-scan block: 256 threads x 4
#define LSHIFT 7         // 128 nodes per fine bucket
#define LMASK 127
#define MAXBUCK 1024     // supports n <= 131072
#define CHUNK 8192       // edges per coarse-pass block

typedef _Float16 f16x8 __attribute__((ext_vector_type(8)));
typedef float f32x4 __attribute__((ext_vector_type(4)));

// ---- pass 1a: per-chunk histogram of coarse buckets -> H[chunk*nbuck + b] ----
__global__ __launch_bounds__(256) void coarse_hist_kernel(const int* __restrict__ dst,
                                                          int* __restrict__ H,
                                                          int E, int nbuck) {
  __shared__ int hist[MAXBUCK];
  for (int i = threadIdx.x; i < nbuck; i += 256) hist[i] = 0;
  __syncthreads();
  int lo = blockIdx.x * CHUNK;
  int hi = min(E, lo + CHUNK);
  for (int i = lo + threadIdx.x; i < hi; i += 256)
    atomicAdd(&hist[dst[i] >> LSHIFT], 1);
  __syncthreads();
  int* Hrow = &H[(size_t)blockIdx.x * nbuck];
  for (int i = threadIdx.x; i < nbuck; i += 256) Hrow[i] = hist[i];
}

// ---- pass 1b: column totals of H -> btotal[b].  One WAVE per bucket. ----
__global__ __launch_bounds__(256) void btotal_kernel(const int* __restrict__ H,
                                                     int* __restrict__ btotal,
                                                     int nchunk, int nbuck) {
  int wv = threadIdx.x >> 6, lane = threadIdx.x & 63;
  int b = blockIdx.x * 4 + wv;
  if (b >= nbuck) return;
  int s = 0;
  for (int c = lane; c < nchunk; c += 64) s += H[(size_t)c * nbuck + b];
#pragma unroll
  for (int off = 1; off < 64; off <<= 1) s += __shfl_xor(s, off);
  if (lane == 0) btotal[b] = s;
}

// ---- pass 1c: exclusive scan of btotal -> bbase[0..nbuck] (single block) ----
__global__ __launch_bounds__(1024) void bbase_scan_kernel(const int* __restrict__ btotal,
                                                          int* __restrict__ bbase, int nbuck) {
  __shared__ int sh[1024];
  int t = threadIdx.x;
  int v = (t < nbuck) ? btotal[t] : 0;
  sh[t] = v;
  __syncthreads();
  for (int off = 1; off < 1024; off <<= 1) {
    int u = (t >= off) ? sh[t - off] : 0;
    __syncthreads();
    sh[t] += u;
    __syncthreads();
  }
  if (t < nbuck) bbase[t] = sh[t] - v;
  if (t == 1023) bbase[nbuck] = sh[1023];
}

// ---- pass 1d: H[c][b] <- bbase[b] + prefix over chunks.  One WAVE per bucket. ----
__global__ __launch_bounds__(256) void chunk_offset_kernel(int* __restrict__ H,
                                                           const int* __restrict__ bbase,
                                                           int nchunk, int nbuck) {
  int wv = threadIdx.x >> 6, lane = threadIdx.x & 63;
  int b = blockIdx.x * 4 + wv;
  if (b >= nbuck) return;
  int run = bbase[b];
  for (int c0 = 0; c0 < nchunk; c0 += 64) {
    int c = c0 + lane;
    int v = (c < nchunk) ? H[(size_t)c * nbuck + b] : 0;
    int incl = v;
#pragma unroll
    for (int off = 1; off < 64; off <<= 1) {
      int u = __shfl_up(incl, off);
      if (lane >= off) incl += u;
    }
    if (c < nchunk) H[(size_t)c * nbuck + b] = run + incl - v;
    run += __shfl(incl, 63);
  }
}

// ---- pass 1e: scatter edges into coarse-bucket runs as packed (src<<7 | dst&127) ----
__global__ __launch_bounds__(256) void coarse_scatter_kernel(const int* __restrict__ src,
                                                             const int* __restrict__ dst,
                                                             const int* __restrict__ H,
                                                             int* __restrict__ packed,
                                                             int E, int nbuck) {
  __shared__ int cur[MAXBUCK];
  const int* Hrow = &H[(size_t)blockIdx.x * nbuck];
  for (int i = threadIdx.x; i < nbuck; i += 256) cur[i] = Hrow[i];
  __syncthreads();
  int lo = blockIdx.x * CHUNK;
  int hi = min(E, lo + CHUNK);
  for (int i = lo + threadIdx.x; i < hi; i += 256) {
    int s = src[i], d = dst[i];
    int b = d >> LSHIFT;
    int pos = atomicAdd(&cur[b], 1);
    packed[pos] = (s << LSHIFT) | (d & LMASK);
  }
}

// ---- pass 2a: per-bucket node-degree histogram -> cnt ----
__global__ __launch_bounds__(256) void fine_count_kernel(const int* __restrict__ packed,
                                                         const int* __restrict__ bbase,
                                                         int* __restrict__ cnt, int n) {
  int b = blockIdx.x;
  __shared__ int hist[128];
  int t = threadIdx.x;
  if (t < 128) hist[t] = 0;
  __syncthreads();
  int e0 = bbase[b], e1 = bbase[b + 1];
  for (int e = e0 + t; e < e1; e += 256) atomicAdd(&hist[packed[e] & LMASK], 1);
  __syncthreads();
  int node = b * 128 + t;
  if (t < 128 && node < n) cnt[node] = hist[t];
}

// ---- pass 2b: per-bucket fill of ssrc ----
__global__ __launch_bounds__(256) void fine_scatter_kernel(const int* __restrict__ packed,
                                                           const int* __restrict__ bbase,
                                                           const int* __restrict__ row_start,
                                                           int* __restrict__ ssrc, int n) {
  int b = blockIdx.x;
  __shared__ int cur[128];
  int t = threadIdx.x;
  if (t < 128) {
    int node = b * 128 + t;
    cur[t] = (node < n) ? row_start[node] : 0;
  }
  __syncthreads();
  int e0 = bbase[b], e1 = bbase[b + 1];
  for (int e = e0 + t; e < e1; e += 256) {
    int p = packed[e];
    int slot = atomicAdd(&cur[p & LMASK], 1);
    ssrc[slot] = p >> LSHIFT;
  }
}

__global__ __launch_bounds__(256) void dinv_kernel(const int* __restrict__ cnt,
                                                   float* __restrict__ dinv, int n) {
  int i = blockIdx.x * 256 + threadIdx.x;
  if (i < n) dinv[i] = 1.0f / sqrtf((float)(cnt[i] + 1));  // +1 = self loop
}

// ---- hierarchical exclusive scan over node counts -> row_start ----

__global__ __launch_bounds__(256) void scan_partial_kernel(const int* __restrict__ cnt,
                                                           int* __restrict__ blocksum,
                                                           int n) {
  int t = threadIdx.x;
  int base = blockIdx.x * SCAN_TILE + t * 4;
  int s = 0;
  if (base + 4 <= n) {
    int4 v = *reinterpret_cast<const int4*>(&cnt[base]);
    s = v.x + v.y + v.z + v.w;
  } else {
    for (int i = 0; i < 4; ++i)
      if (base + i < n) s += cnt[base + i];
  }
#pragma unroll
  for (int off = 1; off < 64; off <<= 1) s += __shfl_xor(s, off);
  __shared__ int wsum[4];
  int lane = t & 63, wv = t >> 6;
  if (lane == 0) wsum[wv] = s;
  __syncthreads();
  if (t == 0) blocksum[blockIdx.x] = wsum[0] + wsum[1] + wsum[2] + wsum[3];
}

__global__ __launch_bounds__(1024) void scan_blocksums_kernel(int* __restrict__ blocksum,
                                                              int* __restrict__ total_out,
                                                              int nb) {
  __shared__ int sh[1024];
  int t = threadIdx.x;
  int v = (t < nb) ? blocksum[t] : 0;
  sh[t] = v;
  __syncthreads();
  for (int off = 1; off < 1024; off <<= 1) {
    int u = (t >= off) ? sh[t - off] : 0;
    __syncthreads();
    sh[t] += u;
    __syncthreads();
  }
  if (t < nb) blocksum[t] = sh[t] - v;  // exclusive
  if (t == 1023) *total_out = sh[1023]; // grand total
}

__global__ __launch_bounds__(256) void scan_final_kernel(const int* __restrict__ cnt,
                                                         const int* __restrict__ blocksum,
                                                         int* __restrict__ row_start, int n) {
  int t = threadIdx.x;
  int base = blockIdx.x * SCAN_TILE + t * 4;
  int v0 = 0, v1 = 0, v2 = 0, v3 = 0;
  if (base + 4 <= n) {
    int4 v = *reinterpret_cast<const int4*>(&cnt[base]);
    v0 = v.x; v1 = v.y; v2 = v.z; v3 = v.w;
  } else {
    if (base + 0 < n) v0 = cnt[base + 0];
    if (base + 1 < n) v1 = cnt[base + 1];
    if (base + 2 < n) v2 = cnt[base + 2];
    if (base + 3 < n) v3 = cnt[base + 3];
  }
  int s = v0 + v1 + v2 + v3;
  __shared__ int sh[256];
  sh[t] = s;
  __syncthreads();
  for (int off = 1; off < 256; off <<= 1) {
    int u = (t >= off) ? sh[t - off] : 0;
    __syncthreads();
    sh[t] += u;
    __syncthreads();
  }
  int run = blocksum[blockIdx.x] + sh[t] - s;
  int p0 = run, p1 = run + v0, p2 = p1 + v1, p3 = p2 + v2;
  if (base + 4 <= n) {
    *reinterpret_cast<int4*>(&row_start[base]) = make_int4(p0, p1, p2, p3);
  } else {
    if (base + 0 < n) row_start[base + 0] = p0;
    if (base + 1 < n) row_start[base + 1] = p1;
    if (base + 2 < n) row_start[base + 2] = p2;
    if (base + 3 < n) row_start[base + 3] = p3;
  }
}

// ---- MFMA fp16 GEMM:  G[r][c] = (X[r][:].W[:][c]) * (DINV?dinv[r]:1) + (BIAS?bias[c]:0)
// v_mfma_f32_16x16x32_f16.  Block = 4 waves x 16 rows = 64 rows.  A fragments
// straight from global (each element read exactly once); W transposed to fp16 LDS
// with +8-half pad (2-way bank alias = free).  Verified layouts:
//   A: row=lane&15, k=(lane>>4)*8+j     B: col=lane&15, k=(lane>>4)*8+j
//   C/D: col=lane&15, row=(lane>>4)*4+reg
// XH: X is fp16; else fp32 (converted in-flight).  OUTH: store __half.
template <int K, int C, bool XH, bool DINV, bool BIAS, bool OUTH>
__global__ __launch_bounds__(256) void mfma_gemm_kernel(const void* __restrict__ Xv,
                                                        const float* __restrict__ W,
                                                        const float* __restrict__ dinv,
                                                        const float* __restrict__ bias,
                                                        void* __restrict__ G, int n) {
  constexpr int KP = K + 8;       // padded LDS pitch in halves (16B-aligned rows)
  constexpr int NT = C / 16;      // n-tiles
  constexpr int KS = K / 32;      // k-steps
  __shared__ _Float16 Wt[C * KP];

  const int tid = threadIdx.x;
  // stage W^T as fp16 (coalesced fp32 reads, scattered LDS writes; once per block)
  for (int idx = tid; idx < K * C; idx += 256) {
    int k = idx / C, c = idx % C;
    Wt[c * KP + k] = (_Float16)W[idx];
  }
  __syncthreads();

  const int wv = tid >> 6, l = tid & 63;
  const int rbase = blockIdx.x * 64 + wv * 16;
  const int kg = (l >> 4) * 8;      // this lane's k-octet base
  const int c16 = l & 15;

  // A fragments: row = rbase + (l&15), k = ks*32 + kg + 0..7
  int arow = rbase + c16;
  if (arow >= n) arow = n - 1;
  f16x8 af[KS];
  if (XH) {
    const _Float16* Xh = reinterpret_cast<const _Float16*>(Xv);
#pragma unroll
    for (int ks = 0; ks < KS; ++ks)
      af[ks] = *reinterpret_cast<const f16x8*>(&Xh[(size_t)arow * K + ks * 32 + kg]);
  } else {
    const float* Xf = reinterpret_cast<const float*>(Xv);
#pragma unroll
    for (int ks = 0; ks < KS; ++ks) {
      float4 u0 = *reinterpret_cast<const float4*>(&Xf[(size_t)arow * K + ks * 32 + kg]);
      float4 u1 = *reinterpret_cast<const float4*>(&Xf[(size_t)arow * K + ks * 32 + kg + 4]);
      f16x8 a;
      a[0] = (_Float16)u0.x; a[1] = (_Float16)u0.y; a[2] = (_Float16)u0.z; a[3] = (_Float16)u0.w;
      a[4] = (_Float16)u1.x; a[5] = (_Float16)u1.y; a[6] = (_Float16)u1.z; a[7] = (_Float16)u1.w;
      af[ks] = a;
    }
  }

  f32x4 acc[NT];
#pragma unroll
  for (int nt = 0; nt < NT; ++nt) acc[nt] = (f32x4){0.f, 0.f, 0.f, 0.f};

#pragma unroll
  for (int ks = 0; ks < KS; ++ks) {
#pragma unroll
    for (int nt = 0; nt < NT; ++nt) {
      f16x8 bf = *reinterpret_cast<const f16x8*>(&Wt[(nt * 16 + c16) * KP + ks * 32 + kg]);
      acc[nt] = __builtin_amdgcn_mfma_f32_16x16x32_f16(af[ks], bf, acc[nt], 0, 0, 0);
    }
  }

  // epilogue: D row = (l>>4)*4 + r, col = l&15
#pragma unroll
  for (int r = 0; r < 4; ++r) {
    int grow = rbase + (l >> 4) * 4 + r;
    if (grow < n) {
      float s = DINV ? dinv[grow] : 1.0f;
#pragma unroll
      for (int nt = 0; nt < NT; ++nt) {
        float v = acc[nt][r] * s;
        if (BIAS) v += bias[nt * 16 + c16];
        if (OUTH)
          reinterpret_cast<__half*>(G)[(size_t)grow * C + nt * 16 + c16] = __float2half(v);
        else
          reinterpret_cast<float*>(G)[(size_t)grow * C + nt * 16 + c16] = v;
      }
    }
  }
}

// out[d][c] = post( dinv[d]*(g[d][c] + sum_{e in row d} g[ssrc[e]][c]) [+ bias[c]] )
// g is fp16 (128B rows, 1 cache line).  One wave per node; lanes split into two
// 32-lane halves processing even/odd edges concurrently.  Each lane holds a half2
// (channels 2q, 2q+1); each gather instruction fetches two rows (256B, 2 edges).
// 8-deep unroll keeps 16 edges (4KB) in flight per wave.  fp32 accumulate; cross-
// half combine via shfl_xor(32).
template <int C, bool RELU, bool BIAS, bool TSCALE, bool OUTH>
__global__ __launch_bounds__(256) void agg_kernel(const __half* __restrict__ g,
                                                  const int* __restrict__ row_start,
                                                  const int* __restrict__ ssrc,
                                                  const float* __restrict__ dinv,
                                                  const float* __restrict__ bias,
                                                  void* __restrict__ out, int n) {
  static_assert(C == 64, "agg assumes 64 channels");
  const int tid = threadIdx.x;
  const int wv = tid >> 6;
  const int lane = tid & 63;
  const int h = lane >> 5;   // half-wave: 0 = even edges (+ self + odd tail), 1 = odd edges
  const int q = lane & 31;   // channel-pair index: channels {2q, 2q+1}
  int node = blockIdx.x * 4 + wv;
  if (node >= n) return;
  const __half2* g2 = reinterpret_cast<const __half2*>(g);

  int e0 = row_start[node];
  int e1 = row_start[node + 1];
  int deg = e1 - e0;
  float2 acc = make_float2(0.f, 0.f);
  if (h == 0) {  // self-loop term, counted once
    float2 sv = __half22float2(g2[(size_t)node * 32 + q]);
    acc.x = sv.x; acc.y = sv.y;
  }
  const int pairs = deg >> 1;
  const int base = e0 + h;  // this half's first edge (stride 2)
  int k = 0;
  for (; k + 8 <= pairs; k += 8) {  // 16 edges in flight per wave
    int idx[8];
#pragma unroll
    for (int i = 0; i < 8; ++i) idx[i] = ssrc[base + 2 * (k + i)];
    __half2 v[8];
#pragma unroll
    for (int i = 0; i < 8; ++i) v[i] = g2[(size_t)idx[i] * 32 + q];
#pragma unroll
    for (int i = 0; i < 8; ++i) {
      float2 f = __half22float2(v[i]);
      acc.x += f.x; acc.y += f.y;
    }
  }
  for (; k + 2 <= pairs; k += 2) {
    int i0 = ssrc[base + 2 * k];
    int i1 = ssrc[base + 2 * (k + 1)];
    float2 f0 = __half22float2(g2[(size_t)i0 * 32 + q]);
    float2 f1 = __half22float2(g2[(size_t)i1 * 32 + q]);
    acc.x += f0.x + f1.x; acc.y += f0.y + f1.y;
  }
  for (; k < pairs; ++k) {
    int i0 = ssrc[base + 2 * k];
    float2 f = __half22float2(g2[(size_t)i0 * 32 + q]);
    acc.x += f.x; acc.y += f.y;
  }
  if (deg & 1) {  // odd edge handled once, by half 0
    if (h == 0) {
      int i0 = ssrc[e1 - 1];
      float2 f = __half22float2(g2[(size_t)i0 * 32 + q]);
      acc.x += f.x; acc.y += f.y;
    }
  }
  // combine even/odd halves
  acc.x += __shfl_xor(acc.x, 32);
  acc.y += __shfl_xor(acc.y, 32);

  if (h == 0) {
    float di = dinv[node];
    float rx = acc.x * di, ry = acc.y * di;
    if (BIAS) {
      float2 bv = *reinterpret_cast<const float2*>(&bias[2 * q]);
      rx += bv.x; ry += bv.y;
    }
    if (RELU) { rx = fmaxf(rx, 0.f); ry = fmaxf(ry, 0.f); }
    if (TSCALE) { rx *= di; ry *= di; }
    if (OUTH) {
      reinterpret_cast<__half2*>(out)[(size_t)node * 32 + q] = __floats2half2_rn(rx, ry);
    } else {
      reinterpret_cast<float2*>(out)[(size_t)node * 32 + q] = make_float2(rx, ry);
    }
  }
}

extern "C" void kernel_launch(void* const* d_in, const int* in_sizes, int n_in,
                              void* d_out, int out_size, void* d_ws, size_t ws_size,
                              hipStream_t stream) {
  const float* x = (const float*)d_in[0];
  const int* ei = (const int*)d_in[1];
  const float* W1 = (const float*)d_in[2];
  const float* b1 = (const float*)d_in[3];
  const float* W2 = (const float*)d_in[4];
  const float* b2 = (const float*)d_in[5];
  const float* W3 = (const float*)d_in[6];
  const float* b3 = (const float*)d_in[7];
  float* out = (float*)d_out;

  const int n = in_sizes[0] / IN_DIM;  // 100000
  const int E = in_sizes[1] / 2;       // 1600000
  const int* src = ei;
  const int* dst = ei + E;
  const int nbuck = (n + LMASK) >> LSHIFT;        // 782
  const int nchunk = (E + CHUNK - 1) / CHUNK;     // 196

  char* p = (char*)d_ws;
  auto alloc = [&](size_t bytes) {
    char* q = p;
    p += (bytes + 255) & ~(size_t)255;
    return q;
  };
  float* dinv = (float*)alloc((size_t)n * 4);
  int* row_start = (int*)alloc((size_t)(n + 1) * 4);
  int* cnt = (int*)alloc((size_t)n * 4);
  int* blocksum = (int*)alloc((size_t)1024 * 4);
  int* btotal = (int*)alloc((size_t)MAXBUCK * 4);
  int* bbase = (int*)alloc((size_t)(MAXBUCK + 1) * 4);
  int* H = (int*)alloc((size_t)nchunk * nbuck * 4);
  int* packed = (int*)alloc((size_t)E * 4);
  int* ssrc = (int*)alloc((size_t)E * 4);
  __half* gh  = (__half*)alloc((size_t)n * HID * 2);  // GEMM1/2 out (gather source)
  __half* h1h = (__half*)alloc((size_t)n * HID * 2);  // agg1 out = h1 (GEMM2 in); reused as z (GEMM3 in)
  __half* th  = (__half*)alloc((size_t)n * HID * 2);  // agg2 out = pre-scaled t (agg3 in)
  __half* zh  = h1h;                                   // alias: h1h dead after GEMM2

  const int NB = (n + SCAN_TILE - 1) / SCAN_TILE;  // 98 node-scan blocks
  const int WGRID = (nbuck + 3) / 4;               // wave-per-bucket grids
  const int GGRID = (n + 63) / 64;                 // MFMA GEMM: 64 rows/block

  // ---- CSR build via 2-pass radix sort (once; shared by all 3 layers) ----
  coarse_hist_kernel<<<nchunk, 256, 0, stream>>>(dst, H, E, nbuck);
  btotal_kernel<<<WGRID, 256, 0, stream>>>(H, btotal, nchunk, nbuck);
  bbase_scan_kernel<<<1, 1024, 0, stream>>>(btotal, bbase, nbuck);
  chunk_offset_kernel<<<WGRID, 256, 0, stream>>>(H, bbase, nchunk, nbuck);
  coarse_scatter_kernel<<<nchunk, 256, 0, stream>>>(src, dst, H, packed, E, nbuck);
  fine_count_kernel<<<nbuck, 256, 0, stream>>>(packed, bbase, cnt, n);
  dinv_kernel<<<(n + 255) / 256, 256, 0, stream>>>(cnt, dinv, n);
  scan_partial_kernel<<<NB, 256, 0, stream>>>(cnt, blocksum, n);
  scan_blocksums_kernel<<<1, 1024, 0, stream>>>(blocksum, &row_start[n], NB);
  scan_final_kernel<<<NB, 256, 0, stream>>>(cnt, blocksum, row_start, n);
  fine_scatter_kernel<<<nbuck, 256, 0, stream>>>(packed, bbase, row_start, ssrc, n);

  // ---- layer 1: g1=(x W1)*dinv_row (fp16) ; h1=relu(agg*dinv + b1) (fp16) ----
  mfma_gemm_kernel<IN_DIM, HID, false, true, false, true><<<GGRID, 256, 0, stream>>>(x, W1, dinv, nullptr, gh, n);
  agg_kernel<HID, true, true, false, true><<<(n + 3) / 4, 256, 0, stream>>>(gh, row_start, ssrc, dinv, b1, h1h, n);

  // ---- layer 2: g2=(h1 W2)*dinv_row (fp16) ; t = relu(agg*dinv + b2)*dinv (fp16, pre-scaled for L3) ----
  mfma_gemm_kernel<HID, HID, true, true, false, true><<<GGRID, 256, 0, stream>>>(h1h, W2, dinv, nullptr, gh, n);
  agg_kernel<HID, true, true, true, true><<<(n + 3) / 4, 256, 0, stream>>>(gh, row_start, ssrc, dinv, b2, th, n);

  // ---- layer 3 (reordered): z = dinv*(t + sum t[s]) (fp16) ; out = z W3 + b3 (fp32) ----
  agg_kernel<HID, false, false, false, true><<<(n + 3) / 4, 256, 0, stream>>>(th, row_start, ssrc, dinv, nullptr, zh, n);
  mfma_gemm_kernel<HID, OUT_DIM, true, false, true, false><<<GGRID, 256, 0, stream>>>(zh, W3, nullptr, b3, out, n);
}